// Round 7
// baseline (600.461 us; speedup 1.0000x reference)
//
#include <hip/hip_runtime.h>
#include <hip/hip_bf16.h>

// ---------- helpers ----------
typedef __bf16 bf16x8 __attribute__((ext_vector_type(8)));
typedef float  f32x4  __attribute__((ext_vector_type(4)));

__device__ __forceinline__ unsigned short f2bf(float f) {
    union { float f; unsigned int u; } v; v.f = f;
    unsigned int u = v.u;
    unsigned int r = (u + 0x7fffu + ((u >> 16) & 1u)) >> 16;   // RNE
    return (unsigned short)r;
}

typedef const __attribute__((address_space(1))) unsigned int* gptr_t;
typedef __attribute__((address_space(3))) unsigned int* lptr_t;
__device__ __forceinline__ void async_ld16(const void* g, void* l) {
    __builtin_amdgcn_global_load_lds((gptr_t)g, (lptr_t)l, 16, 0, 0);
}

// fast GELU (tanh form): max |err| vs exact-erf GELU ~5e-4.
__device__ __forceinline__ float gelu_fast(float x) {
    const float c1 = 2.30223608f;          // 2*sqrt(2/pi)*log2(e)
    const float c2 = 0.102944903f;         // c1 * 0.044715
    float s  = x * x;
    float zn = x * __builtin_fmaf(s, -c2, -c1);
    float u  = __builtin_amdgcn_exp2f(zn);
    return x * __builtin_amdgcn_rcpf(1.0f + u);
}

#define Bn 16384
#define Dd 1024
#define Hh 2048
#define Ee 4
#define Cc 3

// ---------- kernel 0: b1p = b1 ----------
__global__ void init_b1(const float* __restrict__ b1, float* __restrict__ b1p) {
    int i = blockIdx.x * 256 + threadIdx.x;
    b1p[i] = b1[i];
}

// ---------- kernel 1: W1' = diag(ex_ln_g)*W1 transposed to [N][K] bf16,
//                      PLUS bias partials b1p[n] += sum_d ex_ln_b[d]*W1[d][h] ----------
__global__ void prep_w1(const float* __restrict__ w1, const float* __restrict__ exlng,
                        const float* __restrict__ exlnb,
                        unsigned short* __restrict__ w1t, float* __restrict__ b1p) {
    __shared__ float tile[64][65];
    __shared__ float red[4][64];
    const int d0 = blockIdx.x * 64, h0 = blockIdx.y * 64, e = blockIdx.z;
    const int t = threadIdx.x;
    const float* gp = exlng + e * Dd + d0;
    const float* lb = exlnb + e * Dd + d0;
    const float* wp = w1 + ((size_t)e * Dd + d0) * Hh + h0;
    #pragma unroll
    for (int j = 0; j < 16; ++j) {
        int idx = t + j * 256; int dl = idx >> 6, hl = idx & 63;
        tile[dl][hl] = wp[(size_t)dl * Hh + hl];
    }
    __syncthreads();
    #pragma unroll
    for (int j = 0; j < 8; ++j) {
        int idx = t + j * 256; int hl = idx >> 5, k2 = (idx & 31) * 2;
        ushort2 o; o.x = f2bf(tile[k2][hl] * gp[k2]); o.y = f2bf(tile[k2 + 1][hl] * gp[k2 + 1]);
        *(ushort2*)(w1t + ((size_t)(e * Hh + h0 + hl)) * Dd + d0 + k2) = o;
    }
    const int hl = t & 63, dq = t >> 6;
    float acc = 0.f;
    #pragma unroll
    for (int i = 0; i < 16; ++i)
        acc += lb[dq * 16 + i] * tile[dq * 16 + i][hl];
    red[dq][hl] = acc;
    __syncthreads();
    if (t < 64) {
        float s = red[0][t] + red[1][t] + red[2][t] + red[3][t];
        atomicAdd(&b1p[e * Hh + h0 + t], s);
    }
}

// ---------- kernel 3: normalize + gate softmax (wave-per-row, no LDS) ----------
__global__ __launch_bounds__(256) void norm_gate(
        const float* __restrict__ x,
        const float* __restrict__ gg, const float* __restrict__ gb,
        const float* __restrict__ gw, const float* __restrict__ gbias,
        unsigned short* __restrict__ normed,
        float* __restrict__ gate) {
    const int row  = blockIdx.x * 4 + (threadIdx.x >> 6);
    const int lane = threadIdx.x & 63;
    const float4* xp = (const float4*)(x + (size_t)row * Dd);
    float4 v[4];
    float s = 0.f, q = 0.f;
    #pragma unroll
    for (int j = 0; j < 4; ++j) {
        v[j] = xp[j * 64 + lane];
        s += v[j].x + v[j].y + v[j].z + v[j].w;
        q += v[j].x * v[j].x + v[j].y * v[j].y + v[j].z * v[j].z + v[j].w * v[j].w;
    }
    #pragma unroll
    for (int off = 32; off; off >>= 1) { s += __shfl_xor(s, off); q += __shfl_xor(q, off); }
    const float mu = s * (1.f / Dd);
    const float var = q * (1.f / Dd) - mu * mu;
    const float rstd = rsqrtf(var + 1e-5f);
    float l0 = 0.f, l1 = 0.f, l2 = 0.f, l3 = 0.f;
    #pragma unroll
    for (int j = 0; j < 4; ++j) {
        const int d = j * 256 + lane * 4;
        float n[4] = { (v[j].x - mu) * rstd, (v[j].y - mu) * rstd,
                       (v[j].z - mu) * rstd, (v[j].w - mu) * rstd };
        ushort4 u; u.x = f2bf(n[0]); u.y = f2bf(n[1]); u.z = f2bf(n[2]); u.w = f2bf(n[3]);
        ((ushort4*)(normed + (size_t)row * Dd))[j * 64 + lane] = u;
        float4 g4 = ((const float4*)gg)[j * 64 + lane];
        float4 b4 = ((const float4*)gb)[j * 64 + lane];
        float a[4] = { n[0] * g4.x + b4.x, n[1] * g4.y + b4.y,
                       n[2] * g4.z + b4.z, n[3] * g4.w + b4.w };
        #pragma unroll
        for (int c = 0; c < 4; ++c) {
            float4 wv = ((const float4*)gw)[d + c];
            l0 += a[c] * wv.x; l1 += a[c] * wv.y; l2 += a[c] * wv.z; l3 += a[c] * wv.w;
        }
    }
    #pragma unroll
    for (int off = 32; off; off >>= 1) {
        l0 += __shfl_xor(l0, off); l1 += __shfl_xor(l1, off);
        l2 += __shfl_xor(l2, off); l3 += __shfl_xor(l3, off);
    }
    if (lane == 0) {
        float L0 = l0 + gbias[0], L1 = l1 + gbias[1], L2 = l2 + gbias[2], L3 = l3 + gbias[3];
        float mx = fmaxf(fmaxf(L0, L1), fmaxf(L2, L3));
        float e0 = expf(L0 - mx), e1 = expf(L1 - mx), e2 = expf(L2 - mx), e3 = expf(L3 - mx);
        float inv = 1.f / (e0 + e1 + e2 + e3);
        float4 gv; gv.x = e0 * inv; gv.y = e1 * inv; gv.z = e2 * inv; gv.w = e3 * inv;
        ((float4*)gate)[row] = gv;
    }
}

// ---------- kernel 4: 256x256 GEMM, m201-style 4-phase K-iter (BK=64) ----------
// v8: 2 LDS dbuf, 4 phases/K-iter, each: [vmcnt if wait-point; barrier; issue 2
//     gload_lds chunks for kt+1; 4-8 ds_read; setprio; 16 MFMA].
//     Chunk order B0B1|B2B3|A0A2|A1A3 => in-order vmcnt(2) at ph0/ph1 confirms exactly
//     what each phase reads; no drain in main loop (vmcnt(0) only at kt=15).
//     Write-hazard: iter kt stages buf^1; buf^1's last reads (iter kt-1 ph3) complete
//     before the kt-ph0 barrier; stage issues AFTER that barrier. Skew bounded per phase.
//     Swizzle (row stride 128B): slot ^= row&7 on BOTH stage-src and ds_read.
__global__ __launch_bounds__(512, 2) void gemm_fused(
    const unsigned short* __restrict__ A,    // [16384][1024] bf16
    const unsigned short* __restrict__ Bt,   // [8192][1024] bf16 (N-major)
    const float* __restrict__ b1p,           // [8192]
    const float* __restrict__ w2,            // [8192][3]
    float* __restrict__ part)                // [16384][32][3]
{
    __shared__ unsigned short As[2][256 * 64];   // 32 KB each
    __shared__ unsigned short Bs[2][256 * 64];
    __shared__ float w2s[256 * 3];
    __shared__ float b1s[256];

    const int m0 = blockIdx.x * 256;
    const int nb = blockIdx.y;
    const int n0 = nb * 256;
    const int t = threadIdx.x, lane = t & 63, wid = t >> 6;
    const int wm = wid >> 2, wn = wid & 3;          // 2 x 4 wave grid
    const int quad = lane >> 4, l15 = lane & 15;

    if (t < 256) {
        b1s[t] = b1p[n0 + t];
        w2s[t * 3 + 0] = w2[(n0 + t) * 3 + 0];
        w2s[t * 3 + 1] = w2[(n0 + t) * 3 + 1];
        w2s[t * 3 + 2] = w2[(n0 + t) * 3 + 2];
    }

    // staging: thread t -> row t>>3, linear 16B slot t&7; source col pre-swizzled so
    // LDS[row][slot] = global[row][slot ^ (row&7)]. One load covers 64 rows.
    const int srow  = t >> 3;
    const int sslot = (t & 7) ^ ((t >> 3) & 7);
    const unsigned short* ga = A  + (size_t)(m0 + srow) * Dd + sslot * 8;
    const unsigned short* gb = Bt + (size_t)(n0 + srow) * Dd + sslot * 8;

    // stage chunk: rows [r0,r0+64) of k-window kt -> buffer (linear dest, element off)
#define STG_A(kt, r0) async_ld16(ga + (size_t)(r0) * Dd + (kt) * 64, \
                                 &As[(kt) & 1][(r0) * 64 + t * 8])
#define STG_B(kt, r0) async_ld16(gb + (size_t)(r0) * Dd + (kt) * 64, \
                                 &Bs[(kt) & 1][(r0) * 64 + t * 8])

    f32x4 acc[8][4] = {};

    // fragment read addressing (ushort element offsets)
    const int rsw   = l15 & 7;
    const int aRow  = (wm * 128 + l15) * 64;       // + mi*1024 (+4096 for mh1)
    const int bRow  = (wn * 64  + l15) * 64;       // + ni*1024
    const int c0 = ((0 + quad) ^ rsw) * 8;         // ks0 column slot (swizzled)
    const int c1 = ((4 + quad) ^ rsw) * 8;         // ks1

    // prologue: stage iter 0, order B0 B1 B2 B3 A0 A2 | A1 A3 (A1,A3 newest)
    STG_B(0, 0); STG_B(0, 64); STG_B(0, 128); STG_B(0, 192);
    STG_A(0, 0); STG_A(0, 128);
    STG_A(0, 64); STG_A(0, 192);

    for (int kt = 0; kt < 16; ++kt) {
        const unsigned short* as = &As[kt & 1][0];
        const unsigned short* bs = &Bs[kt & 1][0];
        bf16x8 bfr[4], af[4];

        // ---- phase 0: ks0, mi 0-3 ----
        __asm__ volatile("s_waitcnt vmcnt(2)" ::: "memory");   // all but A1,A3(kt) landed
        __builtin_amdgcn_s_barrier();
        if (kt < 15) { STG_B(kt + 1, 0); STG_B(kt + 1, 64); }
        #pragma unroll
        for (int ni = 0; ni < 4; ++ni) bfr[ni] = *(const bf16x8*)(bs + bRow + ni * 1024 + c0);
        #pragma unroll
        for (int mi = 0; mi < 4; ++mi) af[mi] = *(const bf16x8*)(as + aRow + mi * 1024 + c0);
        __builtin_amdgcn_s_setprio(1);
        #pragma unroll
        for (int mi = 0; mi < 4; ++mi)
            #pragma unroll
            for (int ni = 0; ni < 4; ++ni)
                acc[mi][ni] = __builtin_amdgcn_mfma_f32_16x16x32_bf16(af[mi], bfr[ni], acc[mi][ni], 0, 0, 0);
        __builtin_amdgcn_s_setprio(0);

        // ---- phase 1: ks0, mi 4-7 (bfr ks0 held in regs) ----
        if (kt < 15) { __asm__ volatile("s_waitcnt vmcnt(2)" ::: "memory"); }  // A1,A3(kt) landed
        else         { __asm__ volatile("s_waitcnt vmcnt(0)" ::: "memory"); }
        __builtin_amdgcn_s_barrier();
        if (kt < 15) { STG_B(kt + 1, 128); STG_B(kt + 1, 192); }
        #pragma unroll
        for (int mi = 0; mi < 4; ++mi) af[mi] = *(const bf16x8*)(as + aRow + 4096 + mi * 1024 + c0);
        __builtin_amdgcn_s_setprio(1);
        #pragma unroll
        for (int mi = 0; mi < 4; ++mi)
            #pragma unroll
            for (int ni = 0; ni < 4; ++ni)
                acc[mi + 4][ni] = __builtin_amdgcn_mfma_f32_16x16x32_bf16(af[mi], bfr[ni], acc[mi + 4][ni], 0, 0, 0);
        __builtin_amdgcn_s_setprio(0);

        // ---- phase 2: ks1, mi 0-3 ----
        __builtin_amdgcn_s_barrier();
        if (kt < 15) { STG_A(kt + 1, 0); STG_A(kt + 1, 128); }
        #pragma unroll
        for (int ni = 0; ni < 4; ++ni) bfr[ni] = *(const bf16x8*)(bs + bRow + ni * 1024 + c1);
        #pragma unroll
        for (int mi = 0; mi < 4; ++mi) af[mi] = *(const bf16x8*)(as + aRow + mi * 1024 + c1);
        __builtin_amdgcn_s_setprio(1);
        #pragma unroll
        for (int mi = 0; mi < 4; ++mi)
            #pragma unroll
            for (int ni = 0; ni < 4; ++ni)
                acc[mi][ni] = __builtin_amdgcn_mfma_f32_16x16x32_bf16(af[mi], bfr[ni], acc[mi][ni], 0, 0, 0);
        __builtin_amdgcn_s_setprio(0);

        // ---- phase 3: ks1, mi 4-7 ----
        __builtin_amdgcn_s_barrier();
        if (kt < 15) { STG_A(kt + 1, 64); STG_A(kt + 1, 192); }
        #pragma unroll
        for (int mi = 0; mi < 4; ++mi) af[mi] = *(const bf16x8*)(as + aRow + 4096 + mi * 1024 + c1);
        __builtin_amdgcn_s_setprio(1);
        #pragma unroll
        for (int mi = 0; mi < 4; ++mi)
            #pragma unroll
            for (int ni = 0; ni < 4; ++ni)
                acc[mi + 4][ni] = __builtin_amdgcn_mfma_f32_16x16x32_bf16(af[mi], bfr[ni], acc[mi + 4][ni], 0, 0, 0);
        __builtin_amdgcn_s_setprio(0);
    }
#undef STG_A
#undef STG_B

    // epilogue: h = gelu(acc + b1'), partial logits = h @ w2 (3 cols);
    // LDS-reduce over the 4 wn waves, then one plain store per row.
    __syncthreads();                          // all K-loop LDS reads done; reuse As
    float* redb = (float*)&As[0][0];          // [256 rows][4 wn][3] = 12 KB

    #pragma unroll
    for (int mi = 0; mi < 8; ++mi) {
        float pr[4][3];
        #pragma unroll
        for (int r = 0; r < 4; ++r) { pr[r][0] = 0.f; pr[r][1] = 0.f; pr[r][2] = 0.f; }
        #pragma unroll
        for (int ni = 0; ni < 4; ++ni) {
            const int nl = wn * 64 + ni * 16 + l15;
            const float b1v = b1s[nl];
            const float wa = w2s[nl * 3 + 0], wb = w2s[nl * 3 + 1], wc = w2s[nl * 3 + 2];
            #pragma unroll
            for (int r = 0; r < 4; ++r) {
                float xh = acc[mi][ni][r] + b1v;
                float h = gelu_fast(xh);
                pr[r][0] += h * wa; pr[r][1] += h * wb; pr[r][2] += h * wc;
            }
        }
        #pragma unroll
        for (int off = 1; off < 16; off <<= 1) {
            #pragma unroll
            for (int r = 0; r < 4; ++r) {
                pr[r][0] += __shfl_xor(pr[r][0], off);
                pr[r][1] += __shfl_xor(pr[r][1], off);
                pr[r][2] += __shfl_xor(pr[r][2], off);
            }
        }
        if (l15 == 0) {
            #pragma unroll
            for (int r = 0; r < 4; ++r) {
                const int rl = wm * 128 + mi * 16 + quad * 4 + r;   // row within block
                float* rb = redb + (rl * 4 + wn) * 3;
                rb[0] = pr[r][0]; rb[1] = pr[r][1]; rb[2] = pr[r][2];
            }
        }
    }
    __syncthreads();
    if (t < 256) {
        const float* rb = redb + t * 12;
        float o0 = rb[0] + rb[3] + rb[6] + rb[9];
        float o1 = rb[1] + rb[4] + rb[7] + rb[10];
        float o2 = rb[2] + rb[5] + rb[8] + rb[11];
        float* pp = part + (size_t)(m0 + t) * 96 + nb * 3;
        pp[0] = o0; pp[1] = o1; pp[2] = o2;
    }
}

// ---------- kernel 5: out[row] = sum_nb gate[row][nb>>3] * part[row][nb] + gate.b2 ----------
__global__ __launch_bounds__(256) void reduce_out(
        const float* __restrict__ part, const float* __restrict__ gate,
        const float* __restrict__ b2, float* __restrict__ out) {
    const int row = blockIdx.x * 256 + threadIdx.x;
    const float4 gv = ((const float4*)gate)[row];
    const float g[4] = { gv.x, gv.y, gv.z, gv.w };
    float o0 = g[0] * b2[0] + g[1] * b2[3] + g[2] * b2[6] + g[3] * b2[9];
    float o1 = g[0] * b2[1] + g[1] * b2[4] + g[2] * b2[7] + g[3] * b2[10];
    float o2 = g[0] * b2[2] + g[1] * b2[5] + g[2] * b2[8] + g[3] * b2[11];
    const float* pp = part + (size_t)row * 96;
    #pragma unroll
    for (int nb = 0; nb < 32; ++nb) {
        const float ge = g[nb >> 3];
        o0 += ge * pp[nb * 3 + 0];
        o1 += ge * pp[nb * 3 + 1];
        o2 += ge * pp[nb * 3 + 2];
    }
    out[row * 3 + 0] = o0; out[row * 3 + 1] = o1; out[row * 3 + 2] = o2;
}

// ---------- launch ----------
extern "C" void kernel_launch(void* const* d_in, const int* in_sizes, int n_in,
                              void* d_out, int out_size, void* d_ws, size_t ws_size,
                              hipStream_t stream) {
    const float* x     = (const float*)d_in[0];
    const float* gg    = (const float*)d_in[1];
    const float* gb    = (const float*)d_in[2];
    const float* gw    = (const float*)d_in[3];
    const float* gbias = (const float*)d_in[4];
    const float* exlng = (const float*)d_in[5];
    const float* exlnb = (const float*)d_in[6];
    const float* w1    = (const float*)d_in[7];
    const float* b1    = (const float*)d_in[8];
    const float* w2    = (const float*)d_in[9];
    const float* b2    = (const float*)d_in[10];
    float* out = (float*)d_out;

    char* ws = (char*)d_ws;
    unsigned short* normed = (unsigned short*)ws;                         // 16384*1024*2 = 33554432
    unsigned short* w1t    = (unsigned short*)(ws + 33554432);            // 8192*1024*2  = 16777216
    float* b1p  = (float*)(ws + 33554432 + 16777216);                     // 8192*4       = 32768
    float* gate = (float*)(ws + 33554432 + 16777216 + 32768);             // 16384*4*4    = 262144
    float* part = (float*)(ws + 33554432 + 16777216 + 32768 + 262144);    // 16384*32*3*4 = 6291456

    init_b1<<<32, 256, 0, stream>>>(b1, b1p);
    prep_w1<<<dim3(16, 32, 4), 256, 0, stream>>>(w1, exlng, exlnb, w1t, b1p);
    norm_gate<<<4096, 256, 0, stream>>>(x, gg, gb, gw, gbias, normed, gate);
    gemm_fused<<<dim3(64, 32), 512, 0, stream>>>(normed, w1t, b1p, w2, part);
    reduce_out<<<64, 256, 0, stream>>>(part, gate, b2, out);
}

// Round 8
// 473.452 us; speedup vs baseline: 1.2683x; 1.2683x over previous
//
#include <hip/hip_runtime.h>
#include <hip/hip_bf16.h>

// ---------- helpers ----------
typedef __bf16 bf16x8 __attribute__((ext_vector_type(8)));
typedef float  f32x4  __attribute__((ext_vector_type(4)));

__device__ __forceinline__ unsigned short f2bf(float f) {
    union { float f; unsigned int u; } v; v.f = f;
    unsigned int u = v.u;
    unsigned int r = (u + 0x7fffu + ((u >> 16) & 1u)) >> 16;   // RNE
    return (unsigned short)r;
}

typedef const __attribute__((address_space(1))) unsigned int* gptr_t;
typedef __attribute__((address_space(3))) unsigned int* lptr_t;
__device__ __forceinline__ void async_ld16(const void* g, void* l) {
    __builtin_amdgcn_global_load_lds((gptr_t)g, (lptr_t)l, 16, 0, 0);
}

// fast GELU (tanh form): max |err| vs exact-erf GELU ~5e-4.
__device__ __forceinline__ float gelu_fast(float x) {
    const float c1 = 2.30223608f;          // 2*sqrt(2/pi)*log2(e)
    const float c2 = 0.102944903f;         // c1 * 0.044715
    float s  = x * x;
    float zn = x * __builtin_fmaf(s, -c2, -c1);
    float u  = __builtin_amdgcn_exp2f(zn);
    return x * __builtin_amdgcn_rcpf(1.0f + u);
}

#define Bn 16384
#define Dd 1024
#define Hh 2048
#define Ee 4
#define Cc 3

// ---------- kernel 1: FUSED [norm_gate | prep_w1] via blockIdx split ----------
// blocks [0,4096): normalize + gate softmax (wave-per-row).
// blocks [4096,6144): W1' = diag(ex_ln_g)*W1 transposed to [N][K] bf16, plus
//   NON-ATOMIC bias partials b1part[(e*16+d0b)*Hh + h] = sum_{d in d0-block} ln_b[d]*W1[d][h].
__global__ __launch_bounds__(256) void prep_and_norm(
        const float* __restrict__ x,
        const float* __restrict__ gg, const float* __restrict__ gb,
        const float* __restrict__ gw, const float* __restrict__ gbias,
        const float* __restrict__ w1, const float* __restrict__ exlng,
        const float* __restrict__ exlnb,
        unsigned short* __restrict__ normed, float* __restrict__ gate,
        unsigned short* __restrict__ w1t, float* __restrict__ b1part) {
    __shared__ float tile[64][65];
    __shared__ float red[4][64];
    const int bid = blockIdx.x, t = threadIdx.x;

    if (bid < 4096) {
        // ---------------- norm_gate path ----------------
        const int row  = bid * 4 + (t >> 6);
        const int lane = t & 63;
        const float4* xp = (const float4*)(x + (size_t)row * Dd);
        float4 v[4];
        float s = 0.f, q = 0.f;
        #pragma unroll
        for (int j = 0; j < 4; ++j) {
            v[j] = xp[j * 64 + lane];
            s += v[j].x + v[j].y + v[j].z + v[j].w;
            q += v[j].x * v[j].x + v[j].y * v[j].y + v[j].z * v[j].z + v[j].w * v[j].w;
        }
        #pragma unroll
        for (int off = 32; off; off >>= 1) { s += __shfl_xor(s, off); q += __shfl_xor(q, off); }
        const float mu = s * (1.f / Dd);
        const float var = q * (1.f / Dd) - mu * mu;
        const float rstd = rsqrtf(var + 1e-5f);
        float l0 = 0.f, l1 = 0.f, l2 = 0.f, l3 = 0.f;
        #pragma unroll
        for (int j = 0; j < 4; ++j) {
            const int d = j * 256 + lane * 4;
            float n[4] = { (v[j].x - mu) * rstd, (v[j].y - mu) * rstd,
                           (v[j].z - mu) * rstd, (v[j].w - mu) * rstd };
            ushort4 u; u.x = f2bf(n[0]); u.y = f2bf(n[1]); u.z = f2bf(n[2]); u.w = f2bf(n[3]);
            ((ushort4*)(normed + (size_t)row * Dd))[j * 64 + lane] = u;
            float4 g4 = ((const float4*)gg)[j * 64 + lane];
            float4 b4 = ((const float4*)gb)[j * 64 + lane];
            float a[4] = { n[0] * g4.x + b4.x, n[1] * g4.y + b4.y,
                           n[2] * g4.z + b4.z, n[3] * g4.w + b4.w };
            #pragma unroll
            for (int c = 0; c < 4; ++c) {
                float4 wv = ((const float4*)gw)[d + c];
                l0 += a[c] * wv.x; l1 += a[c] * wv.y; l2 += a[c] * wv.z; l3 += a[c] * wv.w;
            }
        }
        #pragma unroll
        for (int off = 32; off; off >>= 1) {
            l0 += __shfl_xor(l0, off); l1 += __shfl_xor(l1, off);
            l2 += __shfl_xor(l2, off); l3 += __shfl_xor(l3, off);
        }
        if (lane == 0) {
            float L0 = l0 + gbias[0], L1 = l1 + gbias[1], L2 = l2 + gbias[2], L3 = l3 + gbias[3];
            float mx = fmaxf(fmaxf(L0, L1), fmaxf(L2, L3));
            float e0 = expf(L0 - mx), e1 = expf(L1 - mx), e2 = expf(L2 - mx), e3 = expf(L3 - mx);
            float inv = 1.f / (e0 + e1 + e2 + e3);
            float4 gv; gv.x = e0 * inv; gv.y = e1 * inv; gv.z = e2 * inv; gv.w = e3 * inv;
            ((float4*)gate)[row] = gv;
        }
    } else {
        // ---------------- prep_w1 path ----------------
        const int b2i = bid - 4096;               // 0..2047
        const int d0b = b2i & 15, h0b = (b2i >> 4) & 31, e = b2i >> 9;
        const int d0 = d0b * 64, h0 = h0b * 64;
        const float* gp = exlng + e * Dd + d0;
        const float* lb = exlnb + e * Dd + d0;
        const float* wp = w1 + ((size_t)e * Dd + d0) * Hh + h0;
        #pragma unroll
        for (int j = 0; j < 16; ++j) {
            int idx = t + j * 256; int dl = idx >> 6, hl = idx & 63;
            tile[dl][hl] = wp[(size_t)dl * Hh + hl];
        }
        __syncthreads();
        #pragma unroll
        for (int j = 0; j < 8; ++j) {
            int idx = t + j * 256; int hl = idx >> 5, k2 = (idx & 31) * 2;
            ushort2 o; o.x = f2bf(tile[k2][hl] * gp[k2]); o.y = f2bf(tile[k2 + 1][hl] * gp[k2 + 1]);
            *(ushort2*)(w1t + ((size_t)(e * Hh + h0 + hl)) * Dd + d0 + k2) = o;
        }
        const int hl = t & 63, dq = t >> 6;
        float acc = 0.f;
        #pragma unroll
        for (int i = 0; i < 16; ++i)
            acc += lb[dq * 16 + i] * tile[dq * 16 + i][hl];
        red[dq][hl] = acc;
        __syncthreads();
        if (t < 64)
            b1part[(size_t)(e * 16 + d0b) * Hh + h0 + t] = red[0][t] + red[1][t] + red[2][t] + red[3][t];
    }
}

// ---------- kernel 2: 256x256 GEMM + GELU + (@W2) -> per-Nblock partial stores ----------
// v9 = v7 core (single-phase K-iter, 4 LDS buffers, 2-tile lead, vmcnt(4)) +
//      XCD-aware block remap: 1-D grid, xcd = L&7; each XCD sweeps a 4-m-block chunk
//      (2 MB of A, L2-resident) across all 32 nb, then the second m-half. Staging
//      becomes L2-hit => latency the 2-tile lead fully covers.
__global__ __launch_bounds__(512, 2) void gemm_fused(
    const unsigned short* __restrict__ A,    // [16384][1024] bf16
    const unsigned short* __restrict__ Bt,   // [8192][1024] bf16 (N-major)
    const float* __restrict__ b1,            // [8192]
    const float* __restrict__ b1part,        // [4*16][2048]
    const float* __restrict__ w2,            // [8192][3]
    float* __restrict__ part)                // [16384][32][3]
{
    __shared__ unsigned short As[4][256 * 32];   // 64 KB
    __shared__ unsigned short Bs[4][256 * 32];   // 64 KB
    __shared__ float w2s[256 * 3];
    __shared__ float b1s[256];

    // XCD-aware remap (bijective): L&7 = XCD (round-robin dispatch), j = L>>3.
    // j = half*128 + nb*4 + mloc  ->  mb = half*32 + xcd*4 + mloc, nb.
    const int L = blockIdx.x;
    const int xcd = L & 7, j = L >> 3;
    const int mb = (j >> 7) * 32 + xcd * 4 + (j & 3);
    const int nb = (j >> 2) & 31;
    const int m0 = mb * 256;
    const int n0 = nb * 256;

    const int t = threadIdx.x, lane = t & 63, wid = t >> 6;
    const int wm = wid >> 2, wn = wid & 3;          // 2 x 4 wave grid
    const int quad = lane >> 4, l15 = lane & 15;

    if (t < 256) {
        const int e = n0 >> 11, hh = n0 & 2047;
        float s = b1[n0 + t];
        #pragma unroll
        for (int i = 0; i < 16; ++i)
            s += b1part[(size_t)(e * 16 + i) * Hh + hh + t];
        b1s[t] = s;
        w2s[t * 3 + 0] = w2[(n0 + t) * 3 + 0];
        w2s[t * 3 + 1] = w2[(n0 + t) * 3 + 1];
        w2s[t * 3 + 2] = w2[(n0 + t) * 3 + 2];
    }

    // staging: thread t -> row t>>2 (sweep adds 128), 16B slot (t&3), source col
    // pre-swizzled so LDS[row][slot] = global[row][slot ^ ((row>>1)&3)].
    const int srow  = t >> 2;
    const int sslot = (t & 3) ^ ((t >> 3) & 3);
    const unsigned short* ga = A  + (size_t)(m0 + srow) * Dd + sslot * 8;
    const unsigned short* gb = Bt + (size_t)(n0 + srow) * Dd + sslot * 8;
    const int ldoff = t * 8;                        // elements; sweep 1 adds 4096

#define STAGE_A(kt) { unsigned short* d = &As[(kt) & 3][ldoff];                 \
    async_ld16(ga + (kt) * 32,            d);                                   \
    async_ld16(ga + (kt) * 32 + 128 * Dd, d + 4096); }
#define STAGE_B(kt) { unsigned short* d = &Bs[(kt) & 3][ldoff];                 \
    async_ld16(gb + (kt) * 32,            d);                                   \
    async_ld16(gb + (kt) * 32 + 128 * Dd, d + 4096); }

    f32x4 acc[8][4] = {};

    // fragment read offsets (elements), swizzled to match staging
    const int rsw   = (l15 >> 1) & 3;
    const int aBase = (wm * 128 + l15) * 32 + ((quad ^ rsw) * 8);
    const int bBase = (wn * 64  + l15) * 32 + ((quad ^ rsw) * 8);

    // prologue: stage tiles 0 and 1; full drain once (cheap, amortized over K)
    STAGE_A(0); STAGE_B(0);
    STAGE_A(1); STAGE_B(1);
    __syncthreads();   // vmcnt(0)+lgkm(0)+barrier: tiles 0,1 landed & visible

    for (int kt = 0; kt < 32; ++kt) {
        const unsigned short* as = &As[kt & 3][0];
        const unsigned short* bs = &Bs[kt & 3][0];

        // reads of tile kt (confirmed at previous tile's barrier)
        bf16x8 bf[4], af[8];
        #pragma unroll
        for (int ni = 0; ni < 4; ++ni) bf[ni] = *(const bf16x8*)(bs + bBase + ni * 512);
        #pragma unroll
        for (int mi = 0; mi < 8; ++mi) af[mi] = *(const bf16x8*)(as + aBase + mi * 512);

        // stage tile kt+2 into free buffer
        if (kt < 30) { STAGE_A(kt + 2); STAGE_B(kt + 2); }

        // counted wait: tile kt+1 landed, tile kt+2 in flight; then converge
        if (kt < 30) {
            __asm__ volatile("s_waitcnt vmcnt(4)" ::: "memory");
        } else {
            __asm__ volatile("s_waitcnt vmcnt(0)" ::: "memory");
        }
        __builtin_amdgcn_s_barrier();
        // pin DS/VMEM below the barrier (no hoisting of next-tile reads); ALU/MFMA free
        __builtin_amdgcn_sched_barrier(0xF);

        __builtin_amdgcn_s_setprio(1);
        #pragma unroll
        for (int mi = 0; mi < 8; ++mi)
            #pragma unroll
            for (int ni = 0; ni < 4; ++ni)
                acc[mi][ni] = __builtin_amdgcn_mfma_f32_16x16x32_bf16(af[mi], bf[ni], acc[mi][ni], 0, 0, 0);
        __builtin_amdgcn_s_setprio(0);
    }
#undef STAGE_A
#undef STAGE_B

    // epilogue: h = gelu(acc + b1'), partial logits = h @ w2 (3 cols);
    // LDS-reduce over the 4 wn waves, then one plain store per row.
    __syncthreads();                          // all K-loop LDS reads done; reuse As
    float* redb = (float*)&As[0][0];          // [256 rows][4 wn][3] = 12 KB

    #pragma unroll
    for (int mi = 0; mi < 8; ++mi) {
        float pr[4][3];
        #pragma unroll
        for (int r = 0; r < 4; ++r) { pr[r][0] = 0.f; pr[r][1] = 0.f; pr[r][2] = 0.f; }
        #pragma unroll
        for (int ni = 0; ni < 4; ++ni) {
            const int nl = wn * 64 + ni * 16 + l15;
            const float b1v = b1s[nl];
            const float wa = w2s[nl * 3 + 0], wb = w2s[nl * 3 + 1], wc = w2s[nl * 3 + 2];
            #pragma unroll
            for (int r = 0; r < 4; ++r) {
                float xh = acc[mi][ni][r] + b1v;
                float h = gelu_fast(xh);
                pr[r][0] += h * wa; pr[r][1] += h * wb; pr[r][2] += h * wc;
            }
        }
        #pragma unroll
        for (int off = 1; off < 16; off <<= 1) {
            #pragma unroll
            for (int r = 0; r < 4; ++r) {
                pr[r][0] += __shfl_xor(pr[r][0], off);
                pr[r][1] += __shfl_xor(pr[r][1], off);
                pr[r][2] += __shfl_xor(pr[r][2], off);
            }
        }
        if (l15 == 0) {
            #pragma unroll
            for (int r = 0; r < 4; ++r) {
                const int rl = wm * 128 + mi * 16 + quad * 4 + r;   // row within block
                float* rb = redb + (rl * 4 + wn) * 3;
                rb[0] = pr[r][0]; rb[1] = pr[r][1]; rb[2] = pr[r][2];
            }
        }
    }
    __syncthreads();
    if (t < 256) {
        const float* rb = redb + t * 12;
        float o0 = rb[0] + rb[3] + rb[6] + rb[9];
        float o1 = rb[1] + rb[4] + rb[7] + rb[10];
        float o2 = rb[2] + rb[5] + rb[8] + rb[11];
        float* pp = part + (size_t)(m0 + t) * 96 + nb * 3;
        pp[0] = o0; pp[1] = o1; pp[2] = o2;
    }
}

// ---------- kernel 3: out[row] = sum_nb gate[row][nb>>3] * part[row][nb] + gate.b2 ----------
__global__ __launch_bounds__(256) void reduce_out(
        const float* __restrict__ part, const float* __restrict__ gate,
        const float* __restrict__ b2, float* __restrict__ out) {
    const int row = blockIdx.x * 256 + threadIdx.x;
    const float4 gv = ((const float4*)gate)[row];
    const float g[4] = { gv.x, gv.y, gv.z, gv.w };
    float o0 = g[0] * b2[0] + g[1] * b2[3] + g[2] * b2[6] + g[3] * b2[9];
    float o1 = g[0] * b2[1] + g[1] * b2[4] + g[2] * b2[7] + g[3] * b2[10];
    float o2 = g[0] * b2[2] + g[1] * b2[5] + g[2] * b2[8] + g[3] * b2[11];
    const float* pp = part + (size_t)row * 96;
    #pragma unroll
    for (int nb = 0; nb < 32; ++nb) {
        const float ge = g[nb >> 3];
        o0 += ge * pp[nb * 3 + 0];
        o1 += ge * pp[nb * 3 + 1];
        o2 += ge * pp[nb * 3 + 2];
    }
    out[row * 3 + 0] = o0; out[row * 3 + 1] = o1; out[row * 3 + 2] = o2;
}

// ---------- launch ----------
extern "C" void kernel_launch(void* const* d_in, const int* in_sizes, int n_in,
                              void* d_out, int out_size, void* d_ws, size_t ws_size,
                              hipStream_t stream) {
    const float* x     = (const float*)d_in[0];
    const float* gg    = (const float*)d_in[1];
    const float* gb    = (const float*)d_in[2];
    const float* gw    = (const float*)d_in[3];
    const float* gbias = (const float*)d_in[4];
    const float* exlng = (const float*)d_in[5];
    const float* exlnb = (const float*)d_in[6];
    const float* w1    = (const float*)d_in[7];
    const float* b1    = (const float*)d_in[8];
    const float* w2    = (const float*)d_in[9];
    const float* b2    = (const float*)d_in[10];
    float* out = (float*)d_out;

    char* ws = (char*)d_ws;
    unsigned short* normed = (unsigned short*)ws;                          // 33554432
    unsigned short* w1t    = (unsigned short*)(ws + 33554432);             // 16777216
    float* b1part = (float*)(ws + 33554432 + 16777216);                    // 4*16*2048*4 = 524288
    float* gate   = (float*)(ws + 33554432 + 16777216 + 524288);           // 262144
    float* part   = (float*)(ws + 33554432 + 16777216 + 524288 + 262144);  // 6291456

    prep_and_norm<<<6144, 256, 0, stream>>>(x, gg, gb, gw, gbias, w1, exlng, exlnb,
                                            normed, gate, w1t, b1part);
    gemm_fused<<<2048, 512, 0, stream>>>(normed, w1t, b1, b1part, w2, part);
    reduce_out<<<64, 256, 0, stream>>>(part, gate, b2, out);
}

// Round 9
// 470.676 us; speedup vs baseline: 1.2757x; 1.0059x over previous
//
#include <hip/hip_runtime.h>
#include <hip/hip_bf16.h>

// ---------- helpers ----------
typedef __bf16 bf16x8 __attribute__((ext_vector_type(8)));
typedef float  f32x4  __attribute__((ext_vector_type(4)));

__device__ __forceinline__ unsigned short f2bf(float f) {
    union { float f; unsigned int u; } v; v.f = f;
    unsigned int u = v.u;
    unsigned int r = (u + 0x7fffu + ((u >> 16) & 1u)) >> 16;   // RNE
    return (unsigned short)r;
}

typedef const __attribute__((address_space(1))) unsigned int* gptr_t;
typedef __attribute__((address_space(3))) unsigned int* lptr_t;
__device__ __forceinline__ void async_ld16(const void* g, void* l) {
    __builtin_amdgcn_global_load_lds((gptr_t)g, (lptr_t)l, 16, 0, 0);
}

// fast GELU (tanh form): max |err| vs exact-erf GELU ~5e-4.
__device__ __forceinline__ float gelu_fast(float x) {
    const float c1 = 2.30223608f;          // 2*sqrt(2/pi)*log2(e)
    const float c2 = 0.102944903f;         // c1 * 0.044715
    float s  = x * x;
    float zn = x * __builtin_fmaf(s, -c2, -c1);
    float u  = __builtin_amdgcn_exp2f(zn);
    return x * __builtin_amdgcn_rcpf(1.0f + u);
}

#define Bn 16384
#define Dd 1024
#define Hh 2048
#define Ee 4
#define Cc 3

// ---------- kernel 1: FUSED [norm_gate | prep_w1] via blockIdx split ----------
__global__ __launch_bounds__(256) void prep_and_norm(
        const float* __restrict__ x,
        const float* __restrict__ gg, const float* __restrict__ gb,
        const float* __restrict__ gw, const float* __restrict__ gbias,
        const float* __restrict__ w1, const float* __restrict__ exlng,
        const float* __restrict__ exlnb,
        unsigned short* __restrict__ normed, float* __restrict__ gate,
        unsigned short* __restrict__ w1t, float* __restrict__ b1part) {
    __shared__ float tile[64][65];
    __shared__ float red[4][64];
    const int bid = blockIdx.x, t = threadIdx.x;

    if (bid < 4096) {
        // ---------------- norm_gate path ----------------
        const int row  = bid * 4 + (t >> 6);
        const int lane = t & 63;
        const float4* xp = (const float4*)(x + (size_t)row * Dd);
        float4 v[4];
        float s = 0.f, q = 0.f;
        #pragma unroll
        for (int j = 0; j < 4; ++j) {
            v[j] = xp[j * 64 + lane];
            s += v[j].x + v[j].y + v[j].z + v[j].w;
            q += v[j].x * v[j].x + v[j].y * v[j].y + v[j].z * v[j].z + v[j].w * v[j].w;
        }
        #pragma unroll
        for (int off = 32; off; off >>= 1) { s += __shfl_xor(s, off); q += __shfl_xor(q, off); }
        const float mu = s * (1.f / Dd);
        const float var = q * (1.f / Dd) - mu * mu;
        const float rstd = rsqrtf(var + 1e-5f);
        float l0 = 0.f, l1 = 0.f, l2 = 0.f, l3 = 0.f;
        #pragma unroll
        for (int j = 0; j < 4; ++j) {
            const int d = j * 256 + lane * 4;
            float n[4] = { (v[j].x - mu) * rstd, (v[j].y - mu) * rstd,
                           (v[j].z - mu) * rstd, (v[j].w - mu) * rstd };
            ushort4 u; u.x = f2bf(n[0]); u.y = f2bf(n[1]); u.z = f2bf(n[2]); u.w = f2bf(n[3]);
            ((ushort4*)(normed + (size_t)row * Dd))[j * 64 + lane] = u;
            float4 g4 = ((const float4*)gg)[j * 64 + lane];
            float4 b4 = ((const float4*)gb)[j * 64 + lane];
            float a[4] = { n[0] * g4.x + b4.x, n[1] * g4.y + b4.y,
                           n[2] * g4.z + b4.z, n[3] * g4.w + b4.w };
            #pragma unroll
            for (int c = 0; c < 4; ++c) {
                float4 wv = ((const float4*)gw)[d + c];
                l0 += a[c] * wv.x; l1 += a[c] * wv.y; l2 += a[c] * wv.z; l3 += a[c] * wv.w;
            }
        }
        #pragma unroll
        for (int off = 32; off; off >>= 1) {
            l0 += __shfl_xor(l0, off); l1 += __shfl_xor(l1, off);
            l2 += __shfl_xor(l2, off); l3 += __shfl_xor(l3, off);
        }
        if (lane == 0) {
            float L0 = l0 + gbias[0], L1 = l1 + gbias[1], L2 = l2 + gbias[2], L3 = l3 + gbias[3];
            float mx = fmaxf(fmaxf(L0, L1), fmaxf(L2, L3));
            float e0 = expf(L0 - mx), e1 = expf(L1 - mx), e2 = expf(L2 - mx), e3 = expf(L3 - mx);
            float inv = 1.f / (e0 + e1 + e2 + e3);
            float4 gv; gv.x = e0 * inv; gv.y = e1 * inv; gv.z = e2 * inv; gv.w = e3 * inv;
            ((float4*)gate)[row] = gv;
        }
    } else {
        // ---------------- prep_w1 path ----------------
        const int b2i = bid - 4096;               // 0..2047
        const int d0b = b2i & 15, h0b = (b2i >> 4) & 31, e = b2i >> 9;
        const int d0 = d0b * 64, h0 = h0b * 64;
        const float* gp = exlng + e * Dd + d0;
        const float* lb = exlnb + e * Dd + d0;
        const float* wp = w1 + ((size_t)e * Dd + d0) * Hh + h0;
        #pragma unroll
        for (int j = 0; j < 16; ++j) {
            int idx = t + j * 256; int dl = idx >> 6, hl = idx & 63;
            tile[dl][hl] = wp[(size_t)dl * Hh + hl];
        }
        __syncthreads();
        #pragma unroll
        for (int j = 0; j < 8; ++j) {
            int idx = t + j * 256; int hl = idx >> 5, k2 = (idx & 31) * 2;
            ushort2 o; o.x = f2bf(tile[k2][hl] * gp[k2]); o.y = f2bf(tile[k2 + 1][hl] * gp[k2 + 1]);
            *(ushort2*)(w1t + ((size_t)(e * Hh + h0 + hl)) * Dd + d0 + k2) = o;
        }
        const int hl = t & 63, dq = t >> 6;
        float acc = 0.f;
        #pragma unroll
        for (int i = 0; i < 16; ++i)
            acc += lb[dq * 16 + i] * tile[dq * 16 + i][hl];
        red[dq][hl] = acc;
        __syncthreads();
        if (t < 64)
            b1part[(size_t)(e * 16 + d0b) * Hh + h0 + t] = red[0][t] + red[1][t] + red[2][t] + red[3][t];
    }
}

// ---------- kernel 2: 256x128 GEMM + GELU + (@W2) -> per-Nblock partial stores ----------
// v10: occupancy fix. Wave-tile 64x64 (acc=64 AGPR, ~115 regs total, launch_bounds(512,4));
//      LDS 74KB (3 buffers) => 2 blocks/CU resident = 4 waves/SIMD. v7's proven lead-2
//      ledger kept verbatim: read kt | stage kt+2 | vmcnt(3) | barrier | MFMA.
//      Two independent blocks per CU interleave: one block's stalls hide under the other.
__global__ __launch_bounds__(512, 4) void gemm_fused(
    const unsigned short* __restrict__ A,    // [16384][1024] bf16
    const unsigned short* __restrict__ Bt,   // [8192][1024] bf16 (N-major)
    const float* __restrict__ b1,            // [8192]
    const float* __restrict__ b1part,        // [4*16][2048]
    const float* __restrict__ w2,            // [8192][3]
    float* __restrict__ part)                // [16384][64][3]
{
    __shared__ unsigned short As[3][256 * 32];   // 48 KB
    __shared__ unsigned short Bs[3][128 * 32];   // 24 KB
    __shared__ float w2s[128 * 3];
    __shared__ float b1s[128];

    const int nb = blockIdx.x;            // 0..63 (fast-varying: neighbors share A panel)
    const int n0 = nb * 128;
    const int m0 = blockIdx.y * 256;

    const int t = threadIdx.x, lane = t & 63, wid = t >> 6;
    const int wm = wid >> 1, wn = wid & 1;          // 4 x 2 wave grid (64x64 tiles)
    const int quad = lane >> 4, l15 = lane & 15;

    if (t < 128) {
        const int e = n0 >> 11, hh = n0 & 2047;
        float s = b1[n0 + t];
        #pragma unroll
        for (int i = 0; i < 16; ++i)
            s += b1part[(size_t)(e * 16 + i) * Hh + hh + t];
        b1s[t] = s;
        w2s[t * 3 + 0] = w2[(n0 + t) * 3 + 0];
        w2s[t * 3 + 1] = w2[(n0 + t) * 3 + 1];
        w2s[t * 3 + 2] = w2[(n0 + t) * 3 + 2];
    }

    // staging: thread t -> row t>>2 (A sweep adds 128), 16B slot (t&3), source col
    // pre-swizzled so LDS[row][slot] = global[row][slot ^ ((row>>1)&3)].
    const int sslot = (t & 3) ^ ((t >> 3) & 3);
    const unsigned short* ga = A  + (size_t)(m0 + (t >> 2)) * Dd + sslot * 8;
    const unsigned short* gb = Bt + (size_t)(n0 + (t >> 2)) * Dd + sslot * 8;   // t>>2 < 128 rows used twice? no: 512 threads cover 128 rows x 4 slots exactly
    const int ldoff = t * 8;   // elements; A sweep 1 adds 4096

#define STAGE_A(kt, bufi) { unsigned short* d = &As[bufi][ldoff];               \
    async_ld16(ga + (kt) * 32,            d);                                   \
    async_ld16(ga + (kt) * 32 + 128 * Dd, d + 4096); }
#define STAGE_B(kt, bufi) { async_ld16(gb + (kt) * 32, &Bs[bufi][ldoff]); }

    f32x4 acc[4][4] = {};

    // fragment read offsets (elements), swizzled to match staging
    const int rsw   = (l15 >> 1) & 3;
    const int aBase = (wm * 64 + l15) * 32 + ((quad ^ rsw) * 8);
    const int bBase = (wn * 64 + l15) * 32 + ((quad ^ rsw) * 8);

    // prologue: stage tiles 0 (buf0) and 1 (buf1); full drain once
    STAGE_A(0, 0); STAGE_B(0, 0);
    STAGE_A(1, 1); STAGE_B(1, 1);
    __syncthreads();

    int rd = 0;                                    // buffer of tile kt; write buf = rd+2 mod 3
    for (int kt = 0; kt < 32; ++kt) {
        const unsigned short* as = &As[rd][0];
        const unsigned short* bs = &Bs[rd][0];
        const int wrb = (rd + 2 >= 3) ? rd - 1 : rd + 2;

        // reads of tile kt (confirmed at previous tile's barrier)
        bf16x8 bf[4], af[4];
        #pragma unroll
        for (int ni = 0; ni < 4; ++ni) bf[ni] = *(const bf16x8*)(bs + bBase + ni * 512);
        #pragma unroll
        for (int mi = 0; mi < 4; ++mi) af[mi] = *(const bf16x8*)(as + aBase + mi * 512);

        // stage tile kt+2 into buffer last read at kt-1 (two barriers back: safe)
        if (kt < 30) { STAGE_A(kt + 2, wrb); STAGE_B(kt + 2, wrb); }

        // counted wait: tile kt+1 landed (issued one full iter ago); kt+2 in flight
        if (kt < 30) {
            __asm__ volatile("s_waitcnt vmcnt(3)" ::: "memory");
        } else {
            __asm__ volatile("s_waitcnt vmcnt(0)" ::: "memory");
        }
        __builtin_amdgcn_s_barrier();
        __builtin_amdgcn_sched_barrier(0xF);   // DS/VMEM stay below barrier; ALU/MFMA free

        __builtin_amdgcn_s_setprio(1);
        #pragma unroll
        for (int mi = 0; mi < 4; ++mi)
            #pragma unroll
            for (int ni = 0; ni < 4; ++ni)
                acc[mi][ni] = __builtin_amdgcn_mfma_f32_16x16x32_bf16(af[mi], bf[ni], acc[mi][ni], 0, 0, 0);
        __builtin_amdgcn_s_setprio(0);

        rd = (rd + 1 >= 3) ? 0 : rd + 1;
    }
#undef STAGE_A
#undef STAGE_B

    // epilogue: h = gelu(acc + b1'), partial logits = h @ w2 (3 cols);
    // LDS-reduce across the 2 wn waves, then one plain store per row.
    __syncthreads();                          // all K-loop LDS reads done; reuse As
    float* redb = (float*)&As[0][0];          // [256 rows][2 wn][3] = 6 KB

    #pragma unroll
    for (int mi = 0; mi < 4; ++mi) {
        float pr[4][3];
        #pragma unroll
        for (int r = 0; r < 4; ++r) { pr[r][0] = 0.f; pr[r][1] = 0.f; pr[r][2] = 0.f; }
        #pragma unroll
        for (int ni = 0; ni < 4; ++ni) {
            const int nl = wn * 64 + ni * 16 + l15;
            const float b1v = b1s[nl];
            const float wa = w2s[nl * 3 + 0], wb = w2s[nl * 3 + 1], wc = w2s[nl * 3 + 2];
            #pragma unroll
            for (int r = 0; r < 4; ++r) {
                float xh = acc[mi][ni][r] + b1v;
                float h = gelu_fast(xh);
                pr[r][0] += h * wa; pr[r][1] += h * wb; pr[r][2] += h * wc;
            }
        }
        #pragma unroll
        for (int off = 1; off < 16; off <<= 1) {
            #pragma unroll
            for (int r = 0; r < 4; ++r) {
                pr[r][0] += __shfl_xor(pr[r][0], off);
                pr[r][1] += __shfl_xor(pr[r][1], off);
                pr[r][2] += __shfl_xor(pr[r][2], off);
            }
        }
        if (l15 == 0) {
            #pragma unroll
            for (int r = 0; r < 4; ++r) {
                const int rl = wm * 64 + mi * 16 + quad * 4 + r;   // row within block
                float* rb = redb + (rl * 2 + wn) * 3;
                rb[0] = pr[r][0]; rb[1] = pr[r][1]; rb[2] = pr[r][2];
            }
        }
    }
    __syncthreads();
    if (t < 256) {
        const float* rb = redb + t * 6;
        float o0 = rb[0] + rb[3];
        float o1 = rb[1] + rb[4];
        float o2 = rb[2] + rb[5];
        float* pp = part + (size_t)(m0 + t) * 192 + nb * 3;
        pp[0] = o0; pp[1] = o1; pp[2] = o2;
    }
}

// ---------- kernel 3: out[row] = sum_nb gate[row][nb>>4] * part[row][nb] + gate.b2 ----------
__global__ __launch_bounds__(256) void reduce_out(
        const float* __restrict__ part, const float* __restrict__ gate,
        const float* __restrict__ b2, float* __restrict__ out) {
    const int row = blockIdx.x * 256 + threadIdx.x;
    const float4 gv = ((const float4*)gate)[row];
    const float g[4] = { gv.x, gv.y, gv.z, gv.w };
    float o0 = g[0] * b2[0] + g[1] * b2[3] + g[2] * b2[6] + g[3] * b2[9];
    float o1 = g[0] * b2[1] + g[1] * b2[4] + g[2] * b2[7] + g[3] * b2[10];
    float o2 = g[0] * b2[2] + g[1] * b2[5] + g[2] * b2[8] + g[3] * b2[11];
    const float* pp = part + (size_t)row * 192;
    #pragma unroll
    for (int nb = 0; nb < 64; ++nb) {
        const float ge = g[nb >> 4];
        o0 += ge * pp[nb * 3 + 0];
        o1 += ge * pp[nb * 3 + 1];
        o2 += ge * pp[nb * 3 + 2];
    }
    out[row * 3 + 0] = o0; out[row * 3 + 1] = o1; out[row * 3 + 2] = o2;
}

// ---------- launch ----------
extern "C" void kernel_launch(void* const* d_in, const int* in_sizes, int n_in,
                              void* d_out, int out_size, void* d_ws, size_t ws_size,
                              hipStream_t stream) {
    const float* x     = (const float*)d_in[0];
    const float* gg    = (const float*)d_in[1];
    const float* gb    = (const float*)d_in[2];
    const float* gw    = (const float*)d_in[3];
    const float* gbias = (const float*)d_in[4];
    const float* exlng = (const float*)d_in[5];
    const float* exlnb = (const float*)d_in[6];
    const float* w1    = (const float*)d_in[7];
    const float* b1    = (const float*)d_in[8];
    const float* w2    = (const float*)d_in[9];
    const float* b2    = (const float*)d_in[10];
    float* out = (float*)d_out;

    char* ws = (char*)d_ws;
    unsigned short* normed = (unsigned short*)ws;                          // 33554432
    unsigned short* w1t    = (unsigned short*)(ws + 33554432);             // 16777216
    float* b1part = (float*)(ws + 33554432 + 16777216);                    // 524288
    float* gate   = (float*)(ws + 33554432 + 16777216 + 524288);           // 262144
    float* part   = (float*)(ws + 33554432 + 16777216 + 524288 + 262144);  // 16384*64*3*4 = 12582912

    prep_and_norm<<<6144, 256, 0, stream>>>(x, gg, gb, gw, gbias, w1, exlng, exlnb,
                                            normed, gate, w1t, b1part);
    gemm_fused<<<dim3(64, 64), 512, 0, stream>>>(normed, w1t, b1, b1part, w2, part);
    reduce_out<<<64, 256, 0, stream>>>(part, gate, b2, out);
}